// Round 1
// baseline (437.877 us; speedup 1.0000x reference)
//
#include <hip/hip_runtime.h>

// Problem constants: B=2, C=64, H=W=256, KS=3, PAD=1, N=9, O=64
// Inputs NCHW fp32; activations internally NHWC bf16: addr = (h*256+w)*64 + c.
// Contraction index k = n*64 + c (n = 3x3 tap, c = channel).

typedef __attribute__((ext_vector_type(8))) short short8;     // 8 bf16 = 4 VGPRs
typedef __attribute__((ext_vector_type(4))) float float4a;    // MFMA accumulator

// fp32 -> bf16 bits, round-to-nearest-even
static __device__ __forceinline__ unsigned short f2bf(float f) {
    unsigned int u = __builtin_bit_cast(unsigned int, f);
    unsigned int r = u + 0x7FFFu + ((u >> 16) & 1u);
    return (unsigned short)(r >> 16);
}
// low/high bf16 of a dword -> fp32 (hi is a single AND)
static __device__ __forceinline__ float bflo(unsigned int u) {
    return __builtin_bit_cast(float, u << 16);
}
static __device__ __forceinline__ float bfhi(unsigned int u) {
    return __builtin_bit_cast(float, u & 0xffff0000u);
}
// bilinear-combine two packed bf16 channels across 4 corners
static __device__ __forceinline__ unsigned int comb2(unsigned int A, unsigned int B,
                                                     unsigned int C, unsigned int D,
                                                     float4 G) {
    const float lo = G.x * bflo(A) + G.y * bflo(B) + G.z * bflo(C) + G.w * bflo(D);
    const float hi = G.x * bfhi(A) + G.y * bfhi(B) + G.z * bfhi(C) + G.w * bfhi(D);
    return (unsigned int)f2bf(lo) | ((unsigned int)f2bf(hi) << 16);
}

// ---------------------------------------------------------------------------
// One kernel packs all four weight tensors (saves 3 launches).
// w_conv [o][c][n] -> bf16 [o][k=n*64+c]; w_off [oc][c][n] -> bf16 [32][k], pad 0.
__global__ __launch_bounds__(256) void k_pack_all(const float* __restrict__ w1,
                                                  const float* __restrict__ w2,
                                                  const float* __restrict__ wo1,
                                                  const float* __restrict__ wo2,
                                                  unsigned short* __restrict__ w1b,
                                                  unsigned short* __restrict__ w2b,
                                                  unsigned short* __restrict__ wob1,
                                                  unsigned short* __restrict__ wob2) {
    int i = blockIdx.x * 256 + threadIdx.x;
    if (i < 36864) {
        int o = i / 576, r = i - o * 576, n = r >> 6, c = r & 63;
        w1b[i] = f2bf(w1[o * 576 + c * 9 + n]);
    } else if (i < 73728) {
        int j = i - 36864;
        int o = j / 576, r = j - o * 576, n = r >> 6, c = r & 63;
        w2b[j] = f2bf(w2[o * 576 + c * 9 + n]);
    } else if (i < 92160) {
        int j = i - 73728;
        int oc = j / 576, r = j - oc * 576, n = r >> 6, c = r & 63;
        wob1[j] = (oc < 18) ? f2bf(wo1[oc * 576 + c * 9 + n]) : (unsigned short)0;
    } else if (i < 110592) {
        int j = i - 92160;
        int oc = j / 576, r = j - oc * 576, n = r >> 6, c = r & 63;
        wob2[j] = (oc < 18) ? f2bf(wo2[oc * 576 + c * 9 + n]) : (unsigned short)0;
    }
}

// ---------------------------------------------------------------------------
// NCHW fp32 [64][65536] -> NHWC bf16 [65536][64]; grid (1024, B).
__global__ __launch_bounds__(256) void k_transpose_bf(const float* __restrict__ x,
                                                      unsigned short* __restrict__ xt) {
    __shared__ float tile[64][65];
    const float* xb = x + (size_t)blockIdx.y * 4194304;
    unsigned short* xtb = xt + (size_t)blockIdx.y * 4194304;
    const int p0 = blockIdx.x << 6;
    const int p = threadIdx.x & 63;
    const int c0 = threadIdx.x >> 6;   // 0..3
    #pragma unroll
    for (int i = 0; i < 16; ++i) {
        const int c = (i << 2) + c0;
        tile[p][c] = xb[(c << 16) + p0 + p];
    }
    __syncthreads();
    const int cq = (threadIdx.x & 15) << 2;
    const int pr0 = threadIdx.x >> 4;
    #pragma unroll
    for (int j = 0; j < 4; ++j) {
        const int pr = (j << 4) + pr0;
        ushort4 u;
        u.x = f2bf(tile[pr][cq + 0]); u.y = f2bf(tile[pr][cq + 1]);
        u.z = f2bf(tile[pr][cq + 2]); u.w = f2bf(tile[pr][cq + 3]);
        *(ushort4*)(xtb + ((p0 + pr) << 6) + cq) = u;
    }
}

// ---------------------------------------------------------------------------
// Fully fused deformable conv layer, bf16 NHWC src.
// NEW STRUCTURE: one WAVE owns one 16-pixel segment end-to-end; zero barriers.
// Key fact: for mfma_f32_16x16x32_bf16, the A-fragment of k-chunk ks=2n+h is
// lane l -> (row = l&15, channels h*32 + (l>>4)*8 .. +7), i.e. pixel l&15,
// channel-octet h*4 + (l>>4). So a lane that gathers (px=l&15, oct=l>>4) and
// (px, oct=(l>>4)+4) produces both A-fragments of tap n IN REGISTERS -- no
// LDS staging tile, no __syncthreads, no cross-wave exchange at all.
// Per-wave LDS: 1152 floats, reused as s_off[16][20] then epilogue transpose.
#define WREG 1152

__global__ __launch_bounds__(256, 4) void k_fused(const unsigned short* __restrict__ src,
                                                  const unsigned short* __restrict__ wob,
                                                  const float* __restrict__ b_off,
                                                  const unsigned short* __restrict__ wtb,
                                                  const float* __restrict__ addsrc,
                                                  void* __restrict__ out,
                                                  int relu, int nhwc_out) {
    __shared__ float s_wave[4 * WREG];   // 18432 B, wave-private regions

    const int b = blockIdx.z;
    const int hrow = blockIdx.y;
    const int tid = threadIdx.x;
    const int lane = tid & 63;
    const int wave = tid >> 6;
    const int l16 = lane & 15;           // = pixel (A rows) = oc (B cols)
    const int q = lane >> 4;             // 0..3
    const int w0 = (blockIdx.x << 6) + (wave << 4);   // this wave's segment
    const unsigned short* srcb = src + ((size_t)b << 22);   // b*65536*64
    float* soff = s_wave + wave * WREG;

    // ============ Phase I: im2col offset conv, A-frags direct ============
    float4a aO0 = {0.f, 0.f, 0.f, 0.f};   // oc 0..15
    float4a aO1 = {0.f, 0.f, 0.f, 0.f};   // oc 16..31 (only 16,17 used)
    {
        const unsigned short* bo0 = wob + l16 * 576 + (q << 3);
        const unsigned short* bo1 = wob + (16 + l16) * 576 + (q << 3);
        #pragma unroll
        for (int n = 0; n < 9; ++n) {
            const int rr = hrow + (n / 3) - 1;
            const int cc = w0 + l16 + (n % 3) - 1;
            const bool inb = (rr >= 0) && (rr < 256) && (cc >= 0) && (cc < 256);
            const int lin = inb ? ((rr << 8) + cc) : 0;
            uint4 v0 = *(const uint4*)(srcb + (lin << 6) + (q << 3));
            uint4 v1 = *(const uint4*)(srcb + (lin << 6) + ((q + 4) << 3));
            if (!inb) { v0.x = v0.y = v0.z = v0.w = 0u; v1.x = v1.y = v1.z = v1.w = 0u; }
            const short8 a0 = __builtin_bit_cast(short8, v0);
            const short8 a1 = __builtin_bit_cast(short8, v1);
            const short8 wf0a = *(const short8*)(bo0 + n * 64);
            const short8 wf0b = *(const short8*)(bo0 + n * 64 + 32);
            const short8 wf1a = *(const short8*)(bo1 + n * 64);
            const short8 wf1b = *(const short8*)(bo1 + n * 64 + 32);
            aO0 = __builtin_amdgcn_mfma_f32_16x16x32_bf16(a0, wf0a, aO0, 0, 0, 0);
            aO0 = __builtin_amdgcn_mfma_f32_16x16x32_bf16(a1, wf0b, aO0, 0, 0, 0);
            aO1 = __builtin_amdgcn_mfma_f32_16x16x32_bf16(a0, wf1a, aO1, 0, 0, 0);
            aO1 = __builtin_amdgcn_mfma_f32_16x16x32_bf16(a1, wf1b, aO1, 0, 0, 0);
        }
    }
    // offsets + bias -> wave-private LDS s_off[16 px][20] (same-wave DS order,
    // no barrier needed). Acc layout: col=oc=l16, row=px=q*4+r.
    {
        const float bia0 = b_off[l16];
        #pragma unroll
        for (int r = 0; r < 4; ++r)
            soff[(q * 4 + r) * 20 + l16] = aO0[r] + bia0;
        if (l16 < 2) {
            const float bia1 = b_off[16 + l16];
            #pragma unroll
            for (int r = 0; r < 4; ++r)
                soff[(q * 4 + r) * 20 + 16 + l16] = aO1[r] + bia1;
        }
    }

    // ============ Phase II: gather + conv MFMA, 9 taps, no barriers ============
    float4a ac0 = {0.f, 0.f, 0.f, 0.f};   // oc  0..15
    float4a ac1 = {0.f, 0.f, 0.f, 0.f};   // oc 16..31
    float4a ac2 = {0.f, 0.f, 0.f, 0.f};   // oc 32..47
    float4a ac3 = {0.f, 0.f, 0.f, 0.f};   // oc 48..63
    {
        const unsigned short* bc = wtb + l16 * 576 + (q << 3);
        #pragma unroll 3
        for (int n = 0; n < 9; ++n) {
            // geometry for (px=l16, tap n) -- 4-way redundant across q, cheap
            const float ox = soff[l16 * 20 + n];
            const float oy = soff[l16 * 20 + 9 + n];
            const float pxx = ox + (float)(hrow + (n / 3));        // h+1 + (n/3-1)
            const float pyy = oy + (float)(w0 + l16 + (n % 3));    // w+1 + (n%3-1)
            const float fx = floorf(pxx), fy = floorf(pyy);
            const float qltx = fminf(fmaxf(fx, 0.f), 257.f);
            const float qlty = fminf(fmaxf(fy, 0.f), 257.f);
            const float qrbx = fminf(fmaxf(fx + 1.f, 0.f), 257.f);
            const float qrby = fminf(fmaxf(fy + 1.f, 0.f), 257.f);
            const float pxc = fminf(fmaxf(pxx, 0.f), 257.f);
            const float pyc = fminf(fmaxf(pyy, 0.f), 257.f);
            const float glt = (1.f + (qltx - pxc)) * (1.f + (qlty - pyc));
            const float grb = (1.f - (qrbx - pxc)) * (1.f - (qrby - pyc));
            const float glb = (1.f + (qltx - pxc)) * (1.f - (qrby - pyc));
            const float grt = (1.f - (qrbx - pxc)) * (1.f + (qlty - pyc));
            const int ilx = (int)qltx, ily = (int)qlty;
            const int irx = (int)qrbx, iry = (int)qrby;
            const bool i0 = (ilx >= 1) && (ilx <= 256) && (ily >= 1) && (ily <= 256);
            const bool i1 = (irx >= 1) && (irx <= 256) && (iry >= 1) && (iry <= 256);
            const bool i2 = (ilx >= 1) && (ilx <= 256) && (iry >= 1) && (iry <= 256);
            const bool i3 = (irx >= 1) && (irx <= 256) && (ily >= 1) && (ily <= 256);
            const int l0 = i0 ? (((ilx - 1) << 8) + (ily - 1)) : 0;
            const int l1 = i1 ? (((irx - 1) << 8) + (iry - 1)) : 0;
            const int l2 = i2 ? (((ilx - 1) << 8) + (iry - 1)) : 0;
            const int l3 = i3 ? (((irx - 1) << 8) + (ily - 1)) : 0;
            float4 G;
            G.x = i0 ? glt : 0.f;
            G.y = i1 ? grb : 0.f;
            G.z = i2 ? glb : 0.f;
            G.w = i3 ? grt : 0.f;

            // 8 batched gather loads: corners x {oct=q, oct=q+4}
            const uint4 A0 = *(const uint4*)(srcb + (l0 << 6) + (q << 3));
            const uint4 B0 = *(const uint4*)(srcb + (l1 << 6) + (q << 3));
            const uint4 C0 = *(const uint4*)(srcb + (l2 << 6) + (q << 3));
            const uint4 D0 = *(const uint4*)(srcb + (l3 << 6) + (q << 3));
            const uint4 A1 = *(const uint4*)(srcb + (l0 << 6) + ((q + 4) << 3));
            const uint4 B1 = *(const uint4*)(srcb + (l1 << 6) + ((q + 4) << 3));
            const uint4 C1 = *(const uint4*)(srcb + (l2 << 6) + ((q + 4) << 3));
            const uint4 D1 = *(const uint4*)(srcb + (l3 << 6) + ((q + 4) << 3));

            uint4 r0, r1;
            r0.x = comb2(A0.x, B0.x, C0.x, D0.x, G);
            r0.y = comb2(A0.y, B0.y, C0.y, D0.y, G);
            r0.z = comb2(A0.z, B0.z, C0.z, D0.z, G);
            r0.w = comb2(A0.w, B0.w, C0.w, D0.w, G);
            r1.x = comb2(A1.x, B1.x, C1.x, D1.x, G);
            r1.y = comb2(A1.y, B1.y, C1.y, D1.y, G);
            r1.z = comb2(A1.z, B1.z, C1.z, D1.z, G);
            r1.w = comb2(A1.w, B1.w, C1.w, D1.w, G);
            const short8 a0 = __builtin_bit_cast(short8, r0);   // A-frag ks=2n
            const short8 a1 = __builtin_bit_cast(short8, r1);   // A-frag ks=2n+1

            const short8 b0a = *(const short8*)(bc + 0 * 9216 + n * 64);
            const short8 b0b = *(const short8*)(bc + 0 * 9216 + n * 64 + 32);
            const short8 b1a = *(const short8*)(bc + 1 * 9216 + n * 64);
            const short8 b1b = *(const short8*)(bc + 1 * 9216 + n * 64 + 32);
            const short8 b2a = *(const short8*)(bc + 2 * 9216 + n * 64);
            const short8 b2b = *(const short8*)(bc + 2 * 9216 + n * 64 + 32);
            const short8 b3a = *(const short8*)(bc + 3 * 9216 + n * 64);
            const short8 b3b = *(const short8*)(bc + 3 * 9216 + n * 64 + 32);
            ac0 = __builtin_amdgcn_mfma_f32_16x16x32_bf16(a0, b0a, ac0, 0, 0, 0);
            ac0 = __builtin_amdgcn_mfma_f32_16x16x32_bf16(a1, b0b, ac0, 0, 0, 0);
            ac1 = __builtin_amdgcn_mfma_f32_16x16x32_bf16(a0, b1a, ac1, 0, 0, 0);
            ac1 = __builtin_amdgcn_mfma_f32_16x16x32_bf16(a1, b1b, ac1, 0, 0, 0);
            ac2 = __builtin_amdgcn_mfma_f32_16x16x32_bf16(a0, b2a, ac2, 0, 0, 0);
            ac2 = __builtin_amdgcn_mfma_f32_16x16x32_bf16(a1, b2b, ac2, 0, 0, 0);
            ac3 = __builtin_amdgcn_mfma_f32_16x16x32_bf16(a0, b3a, ac3, 0, 0, 0);
            ac3 = __builtin_amdgcn_mfma_f32_16x16x32_bf16(a1, b3b, ac3, 0, 0, 0);
        }
    }

    // ============ Epilogue: wave-private LDS transpose, no barriers ============
    // acc layout: col=oc=l16 (+16*j), row=px=q*4+r.
    float* st = soff;   // safe: same-wave DS ordering, soff reads are done
    if (nhwc_out) {
        // st[px][oc], stride 65 (<=2-way banks both sides)
        #pragma unroll
        for (int r = 0; r < 4; ++r) {
            const int px = q * 4 + r;
            st[px * 65 + l16 +  0] = ac0[r];
            st[px * 65 + l16 + 16] = ac1[r];
            st[px * 65 + l16 + 32] = ac2[r];
            st[px * 65 + l16 + 48] = ac3[r];
        }
        unsigned short* ob = (unsigned short*)out + ((size_t)b << 22);
        #pragma unroll
        for (int it = 0; it < 2; ++it) {
            const int idx = it * 64 + lane;
            const int p = idx >> 3;            // 0..15
            const int o8 = (idx & 7) << 3;     // 0,8,..,56
            const float* sr = st + p * 65 + o8;
            float v[8];
            #pragma unroll
            for (int j = 0; j < 8; ++j) {
                float t = sr[j];
                if (relu) t = fmaxf(t, 0.f);
                v[j] = t;
            }
            uint4 u;
            u.x = (unsigned int)f2bf(v[0]) | ((unsigned int)f2bf(v[1]) << 16);
            u.y = (unsigned int)f2bf(v[2]) | ((unsigned int)f2bf(v[3]) << 16);
            u.z = (unsigned int)f2bf(v[4]) | ((unsigned int)f2bf(v[5]) << 16);
            u.w = (unsigned int)f2bf(v[6]) | ((unsigned int)f2bf(v[7]) << 16);
            *(uint4*)(ob + (((hrow << 8) + w0 + p) << 6) + o8) = u;
        }
    } else {
        // NCHW fp32 + optional residual: st[oc][px], stride 17
        #pragma unroll
        for (int r = 0; r < 4; ++r) {
            const int px = q * 4 + r;
            st[(l16 +  0) * 17 + px] = ac0[r];
            st[(l16 + 16) * 17 + px] = ac1[r];
            st[(l16 + 32) * 17 + px] = ac2[r];
            st[(l16 + 48) * 17 + px] = ac3[r];
        }
        float* obf = (float*)out + ((size_t)b << 22);
        const float* ab = (addsrc != nullptr) ? (addsrc + ((size_t)b << 22)) : nullptr;
        #pragma unroll
        for (int it = 0; it < 4; ++it) {
            const int idx = it * 64 + lane;
            const int oo = idx >> 2;           // 0..63
            const int p4 = (idx & 3) << 2;     // 0,4,8,12
            float v0 = st[oo * 17 + p4 + 0];
            float v1 = st[oo * 17 + p4 + 1];
            float v2 = st[oo * 17 + p4 + 2];
            float v3 = st[oo * 17 + p4 + 3];
            if (relu) {
                v0 = fmaxf(v0, 0.f); v1 = fmaxf(v1, 0.f);
                v2 = fmaxf(v2, 0.f); v3 = fmaxf(v3, 0.f);
            }
            const int g = (oo << 16) + (hrow << 8) + w0 + p4;
            if (ab != nullptr) {
                const float4 rv = *(const float4*)(ab + g);
                v0 += rv.x; v1 += rv.y; v2 += rv.z; v3 += rv.w;
            }
            float4 vv; vv.x = v0; vv.y = v1; vv.z = v2; vv.w = v3;
            *(float4*)(obf + g) = vv;
        }
    }
}

// ---------------------------------------------------------------------------
extern "C" void kernel_launch(void* const* d_in, const int* in_sizes, int n_in,
                              void* d_out, int out_size, void* d_ws, size_t ws_size,
                              hipStream_t stream) {
    const float* x      = (const float*)d_in[0];
    const float* w_off1 = (const float*)d_in[1];
    const float* b_off1 = (const float*)d_in[2];
    const float* w1     = (const float*)d_in[3];
    const float* w_off2 = (const float*)d_in[4];
    const float* b_off2 = (const float*)d_in[5];
    const float* w2     = (const float*)d_in[6];
    float* outp = (float*)d_out;

    // workspace: 16 MB xT(bf16) + 16 MB midT(bf16) + packed weights = 32.2 MB
    char* ws = (char*)d_ws;
    unsigned short* xT   = (unsigned short*)ws;                     // 16777216 B
    unsigned short* midT = (unsigned short*)(ws + 16777216);        // 16777216 B
    unsigned short* w1b  = (unsigned short*)(ws + 33554432);                    // 73728
    unsigned short* w2b  = (unsigned short*)(ws + 33554432 + 73728);            // 73728
    unsigned short* wob1 = (unsigned short*)(ws + 33554432 + 2 * 73728);        // 36864
    unsigned short* wob2 = (unsigned short*)(ws + 33554432 + 2 * 73728 + 36864);// 36864

    k_pack_all<<<432, 256, 0, stream>>>(w1, w2, w_off1, w_off2, w1b, w2b, wob1, wob2);

    dim3 gT(1024, 2);
    k_transpose_bf<<<gT, 256, 0, stream>>>(x, xT);

    dim3 gDef(4, 256, 2);   // (W/64 block-x, H, B); one wave per 16-px segment
    // layer 1: offsets + deform-conv(x), ReLU -> midT (NHWC bf16)
    k_fused<<<gDef, 256, 0, stream>>>(xT, wob1, b_off1, w1b, nullptr, midT, 1, 1);
    // layer 2: offsets + deform-conv(mid), + x residual -> out (NCHW fp32)
    k_fused<<<gDef, 256, 0, stream>>>(midT, wob2, b_off2, w2b, x, outp, 0, 0);
}

// Round 2
// 342.691 us; speedup vs baseline: 1.2778x; 1.2778x over previous
//
#include <hip/hip_runtime.h>

// Problem constants: B=2, C=64, H=W=256, KS=3, PAD=1, N=9, O=64
// Inputs NCHW fp32; activations internally NHWC bf16: addr = (h*256+w)*64 + c.
// Contraction index k = n*64 + c (n = 3x3 tap, c = channel).

typedef __attribute__((ext_vector_type(8))) short short8;     // 8 bf16 = 4 VGPRs
typedef __attribute__((ext_vector_type(4))) float float4a;    // MFMA accumulator

// packed fp32x2 -> bf16x2 via HW cvt (RNE), 1 VALU op (gfx950; no builtin)
static __device__ __forceinline__ unsigned int cvtpk(float lo, float hi) {
    unsigned int r;
    asm("v_cvt_pk_bf16_f32 %0, %1, %2" : "=v"(r) : "v"(lo), "v"(hi));
    return r;
}
// single fp32 -> bf16 bits
static __device__ __forceinline__ unsigned short f2bf(float f) {
    return (unsigned short)(cvtpk(f, f) & 0xffffu);
}
// low/high bf16 of a dword -> fp32 (hi is a single AND)
static __device__ __forceinline__ float bflo(unsigned int u) {
    return __builtin_bit_cast(float, u << 16);
}
static __device__ __forceinline__ float bfhi(unsigned int u) {
    return __builtin_bit_cast(float, u & 0xffff0000u);
}
// bilinear-combine two packed bf16 channels across 4 corners
static __device__ __forceinline__ unsigned int comb2(unsigned int A, unsigned int B,
                                                     unsigned int C, unsigned int D,
                                                     float4 G) {
    const float lo = G.x * bflo(A) + G.y * bflo(B) + G.z * bflo(C) + G.w * bflo(D);
    const float hi = G.x * bfhi(A) + G.y * bfhi(B) + G.z * bfhi(C) + G.w * bfhi(D);
    return cvtpk(lo, hi);
}

// ---------------------------------------------------------------------------
// One kernel packs all four weight tensors (saves 3 launches).
// w_conv [o][c][n] -> bf16 [o][k=n*64+c]; w_off [oc][c][n] -> bf16 [32][k], pad 0.
__global__ __launch_bounds__(256) void k_pack_all(const float* __restrict__ w1,
                                                  const float* __restrict__ w2,
                                                  const float* __restrict__ wo1,
                                                  const float* __restrict__ wo2,
                                                  unsigned short* __restrict__ w1b,
                                                  unsigned short* __restrict__ w2b,
                                                  unsigned short* __restrict__ wob1,
                                                  unsigned short* __restrict__ wob2) {
    int i = blockIdx.x * 256 + threadIdx.x;
    if (i < 36864) {
        int o = i / 576, r = i - o * 576, n = r >> 6, c = r & 63;
        w1b[i] = f2bf(w1[o * 576 + c * 9 + n]);
    } else if (i < 73728) {
        int j = i - 36864;
        int o = j / 576, r = j - o * 576, n = r >> 6, c = r & 63;
        w2b[j] = f2bf(w2[o * 576 + c * 9 + n]);
    } else if (i < 92160) {
        int j = i - 73728;
        int oc = j / 576, r = j - oc * 576, n = r >> 6, c = r & 63;
        wob1[j] = (oc < 18) ? f2bf(wo1[oc * 576 + c * 9 + n]) : (unsigned short)0;
    } else if (i < 110592) {
        int j = i - 92160;
        int oc = j / 576, r = j - oc * 576, n = r >> 6, c = r & 63;
        wob2[j] = (oc < 18) ? f2bf(wo2[oc * 576 + c * 9 + n]) : (unsigned short)0;
    }
}

// ---------------------------------------------------------------------------
// NCHW fp32 [64][65536] -> NHWC bf16 [65536][64]; grid (1024, B).
__global__ __launch_bounds__(256) void k_transpose_bf(const float* __restrict__ x,
                                                      unsigned short* __restrict__ xt) {
    __shared__ float tile[64][65];
    const float* xb = x + (size_t)blockIdx.y * 4194304;
    unsigned short* xtb = xt + (size_t)blockIdx.y * 4194304;
    const int p0 = blockIdx.x << 6;
    const int p = threadIdx.x & 63;
    const int c0 = threadIdx.x >> 6;   // 0..3
    #pragma unroll
    for (int i = 0; i < 16; ++i) {
        const int c = (i << 2) + c0;
        tile[p][c] = xb[(c << 16) + p0 + p];
    }
    __syncthreads();
    const int cq = (threadIdx.x & 15) << 2;
    const int pr0 = threadIdx.x >> 4;
    #pragma unroll
    for (int j = 0; j < 4; ++j) {
        const int pr = (j << 4) + pr0;
        uint2 u;
        u.x = cvtpk(tile[pr][cq + 0], tile[pr][cq + 1]);
        u.y = cvtpk(tile[pr][cq + 2], tile[pr][cq + 3]);
        *(uint2*)(xtb + ((p0 + pr) << 6) + cq) = u;
    }
}

// ---------------------------------------------------------------------------
// Fully fused deformable conv layer, bf16 NHWC src. Block = 256 thr = 4 waves,
// one block per (h, 16-px segment, batch). Memory phases are straight-line
// branchless with explicit load batches (ILP); MFMA B-operands preloaded to
// registers so MFMA loops only wait on LDS.
// Tap split: g=0 -> {0,2,4,6,8}; g=1 -> {1,3,5,7,7(dup, benign)}.
// vs round-0: geometry computed in-register (no s_aux, one fewer barrier),
// cvt_pk packing, direct NCHW epilogue stores. LDS 19968 B.
#define XSTR 584   // s_xoff row stride (bf16): dword stride 292 = 4 mod 32

__global__ __launch_bounds__(256, 4) void k_fused(const unsigned short* __restrict__ src,
                                                  const unsigned short* __restrict__ wob,
                                                  const float* __restrict__ b_off,
                                                  const unsigned short* __restrict__ wtb,
                                                  const float* __restrict__ addsrc,
                                                  void* __restrict__ out,
                                                  int relu, int nhwc_out) {
    __shared__ unsigned short s_xoff[16 * XSTR];   // 18688 B
    __shared__ float          s_off[16 * 20];      // 1280 B   (total 19968 B)

    const int b = blockIdx.z;
    const int h = blockIdx.y;
    const int w0 = blockIdx.x << 4;
    const int tid = threadIdx.x;
    const int lane = tid & 63;
    const int wave = tid >> 6;
    const int quad = lane >> 4;
    const int l16 = lane & 15;

    const int px = tid >> 4;          // pixel 0..15
    const int oct = tid & 7;          // channel octet (8 bf16 = 16 B)
    const int g = (tid >> 3) & 1;     // tap group
    const unsigned short* srcb = src + ((size_t)b << 22);   // b*65536*64

    // this thread's 5 taps (compile-time-foldable selects)
    const int nT[5] = {g ? 1 : 0, g ? 3 : 2, g ? 5 : 4, g ? 7 : 6, g ? 7 : 8};
    const int rT[5] = {-1, g ? 0 : -1, 0, 1, 1};                  // n/3 - 1
    const int cT[5] = {g ? 0 : -1, g ? -1 : 1, g ? 1 : 0, g ? 0 : -1, g ? 0 : 1};  // n%3 - 1

    // ========== Stage 1: im2col 3x3, branchless, all 5 loads batched ==========
    {
        uint4 sv[5];
        #pragma unroll
        for (int t = 0; t < 5; ++t) {
            const int row = h + rT[t];
            const int col = w0 + px + cT[t];
            const bool inb = (row >= 0) && (row < 256) && (col >= 0) && (col < 256);
            const int lin = inb ? ((row << 8) + col) : 0;
            uint4 v = *(const uint4*)(srcb + (lin << 6) + (oct << 3));
            if (!inb) { v.x = 0u; v.y = 0u; v.z = 0u; v.w = 0u; }
            sv[t] = v;
        }
        #pragma unroll
        for (int t = 0; t < 5; ++t)
            *(uint4*)(s_xoff + px * XSTR + (nT[t] << 6) + (oct << 3)) = sv[t];
    }

    // Preload offset-conv B fragments on waves 0,1 (overlaps the barrier).
    short8 wf[18];
    if (wave < 2) {
        const unsigned short* brow = wob + (wave * 16 + l16) * 576 + quad * 8;
        #pragma unroll
        for (int ks = 0; ks < 18; ++ks)
            wf[ks] = *(const short8*)(brow + ks * 32);
    }
    __syncthreads();

    // ============ Stage 2: offset MFMA (waves 0,1 cover 32 oc) ============
    if (wave < 2) {
        float4a acc = {0.f, 0.f, 0.f, 0.f};
        const unsigned short* arow = s_xoff + l16 * XSTR + quad * 8;
        #pragma unroll
        for (int ks = 0; ks < 18; ++ks) {
            const short8 a = *(const short8*)(arow + ks * 32);
            acc = __builtin_amdgcn_mfma_f32_16x16x32_bf16(a, wf[ks], acc, 0, 0, 0);
        }
        const int oc = wave * 16 + l16;
        if (oc < 18) {
            const float bia = b_off[oc];
            #pragma unroll
            for (int r = 0; r < 4; ++r)
                s_off[(quad * 4 + r) * 20 + oc] = acc[r] + bia;
        }
    }
    __syncthreads();

    // ====== Stage 3: geometry in-register + bilinear gather, batched ======
    short8 bfrag[18];   // conv B fragments, preloaded in two chunks below
    {
        const unsigned short* brow = wtb + (wave * 16 + l16) * 576 + quad * 8;

        // geometry for this thread's 5 taps (redundant across oct group; VALU
        // overlaps memory stalls; replaces the old 144-thread phase + barrier)
        int4 L[5]; float4 G[5];
        const float fh = (float)(h + 1);
        const float fw = (float)(w0 + px + 1);
        #pragma unroll
        for (int t = 0; t < 5; ++t) {
            const int n = nT[t];
            const float ox = s_off[px * 20 + n];
            const float oy = s_off[px * 20 + 9 + n];
            const float pxx = ox + fh + (float)rT[t];
            const float pyy = oy + fw + (float)cT[t];
            const float fx = floorf(pxx), fy = floorf(pyy);
            const float qltx = fminf(fmaxf(fx, 0.f), 257.f);
            const float qlty = fminf(fmaxf(fy, 0.f), 257.f);
            const float qrbx = fminf(fmaxf(fx + 1.f, 0.f), 257.f);
            const float qrby = fminf(fmaxf(fy + 1.f, 0.f), 257.f);
            const float pxc = fminf(fmaxf(pxx, 0.f), 257.f);
            const float pyc = fminf(fmaxf(pyy, 0.f), 257.f);
            const float glt = (1.f + (qltx - pxc)) * (1.f + (qlty - pyc));
            const float grb = (1.f - (qrbx - pxc)) * (1.f - (qrby - pyc));
            const float glb = (1.f + (qltx - pxc)) * (1.f - (qrby - pyc));
            const float grt = (1.f - (qrbx - pxc)) * (1.f + (qlty - pyc));
            const int ilx = (int)qltx, ily = (int)qlty;
            const int irx = (int)qrbx, iry = (int)qrby;
            const bool b0 = (ilx >= 1) && (ilx <= 256) && (ily >= 1) && (ily <= 256);
            const bool b1 = (irx >= 1) && (irx <= 256) && (iry >= 1) && (iry <= 256);
            const bool b2 = (ilx >= 1) && (ilx <= 256) && (iry >= 1) && (iry <= 256);
            const bool b3 = (irx >= 1) && (irx <= 256) && (ily >= 1) && (ily <= 256);
            int4 li;
            li.x = b0 ? (((ilx - 1) << 8) + (ily - 1)) : 0;
            li.y = b1 ? (((irx - 1) << 8) + (iry - 1)) : 0;
            li.z = b2 ? (((ilx - 1) << 8) + (iry - 1)) : 0;
            li.w = b3 ? (((irx - 1) << 8) + (ily - 1)) : 0;
            L[t] = li;
            float4 gg;
            gg.x = b0 ? glt : 0.f;
            gg.y = b1 ? grb : 0.f;
            gg.z = b2 ? glb : 0.f;
            gg.w = b3 ? grt : 0.f;
            G[t] = gg;
        }

        // ---- round A: taps 0..2, 12 loads in flight ----
        uint4 A0, B0, C0, D0, A1, B1, C1, D1, A2, B2, C2, D2;
        A0 = *(const uint4*)(srcb + (L[0].x << 6) + (oct << 3));
        B0 = *(const uint4*)(srcb + (L[0].y << 6) + (oct << 3));
        C0 = *(const uint4*)(srcb + (L[0].z << 6) + (oct << 3));
        D0 = *(const uint4*)(srcb + (L[0].w << 6) + (oct << 3));
        A1 = *(const uint4*)(srcb + (L[1].x << 6) + (oct << 3));
        B1 = *(const uint4*)(srcb + (L[1].y << 6) + (oct << 3));
        C1 = *(const uint4*)(srcb + (L[1].z << 6) + (oct << 3));
        D1 = *(const uint4*)(srcb + (L[1].w << 6) + (oct << 3));
        A2 = *(const uint4*)(srcb + (L[2].x << 6) + (oct << 3));
        B2 = *(const uint4*)(srcb + (L[2].y << 6) + (oct << 3));
        C2 = *(const uint4*)(srcb + (L[2].z << 6) + (oct << 3));
        D2 = *(const uint4*)(srcb + (L[2].w << 6) + (oct << 3));
        {
            uint4 r;
            r.x = comb2(A0.x, B0.x, C0.x, D0.x, G[0]);
            r.y = comb2(A0.y, B0.y, C0.y, D0.y, G[0]);
            r.z = comb2(A0.z, B0.z, C0.z, D0.z, G[0]);
            r.w = comb2(A0.w, B0.w, C0.w, D0.w, G[0]);
            *(uint4*)(s_xoff + px * XSTR + (nT[0] << 6) + (oct << 3)) = r;
            r.x = comb2(A1.x, B1.x, C1.x, D1.x, G[1]);
            r.y = comb2(A1.y, B1.y, C1.y, D1.y, G[1]);
            r.z = comb2(A1.z, B1.z, C1.z, D1.z, G[1]);
            r.w = comb2(A1.w, B1.w, C1.w, D1.w, G[1]);
            *(uint4*)(s_xoff + px * XSTR + (nT[1] << 6) + (oct << 3)) = r;
            r.x = comb2(A2.x, B2.x, C2.x, D2.x, G[2]);
            r.y = comb2(A2.y, B2.y, C2.y, D2.y, G[2]);
            r.z = comb2(A2.z, B2.z, C2.z, D2.z, G[2]);
            r.w = comb2(A2.w, B2.w, C2.w, D2.w, G[2]);
            *(uint4*)(s_xoff + px * XSTR + (nT[2] << 6) + (oct << 3)) = r;
        }

        // ---- round B: taps 3..4 (8 loads) + first 12 bfrag loads in flight ----
        uint4 A3, B3, C3, D3, A4, B4, C4, D4;
        A3 = *(const uint4*)(srcb + (L[3].x << 6) + (oct << 3));
        B3 = *(const uint4*)(srcb + (L[3].y << 6) + (oct << 3));
        C3 = *(const uint4*)(srcb + (L[3].z << 6) + (oct << 3));
        D3 = *(const uint4*)(srcb + (L[3].w << 6) + (oct << 3));
        A4 = *(const uint4*)(srcb + (L[4].x << 6) + (oct << 3));
        B4 = *(const uint4*)(srcb + (L[4].y << 6) + (oct << 3));
        C4 = *(const uint4*)(srcb + (L[4].z << 6) + (oct << 3));
        D4 = *(const uint4*)(srcb + (L[4].w << 6) + (oct << 3));
        #pragma unroll
        for (int ks = 0; ks < 12; ++ks)
            bfrag[ks] = *(const short8*)(brow + ks * 32);
        {
            uint4 r;
            r.x = comb2(A3.x, B3.x, C3.x, D3.x, G[3]);
            r.y = comb2(A3.y, B3.y, C3.y, D3.y, G[3]);
            r.z = comb2(A3.z, B3.z, C3.z, D3.z, G[3]);
            r.w = comb2(A3.w, B3.w, C3.w, D3.w, G[3]);
            *(uint4*)(s_xoff + px * XSTR + (nT[3] << 6) + (oct << 3)) = r;
            r.x = comb2(A4.x, B4.x, C4.x, D4.x, G[4]);
            r.y = comb2(A4.y, B4.y, C4.y, D4.y, G[4]);
            r.z = comb2(A4.z, B4.z, C4.z, D4.z, G[4]);
            r.w = comb2(A4.w, B4.w, C4.w, D4.w, G[4]);
            *(uint4*)(s_xoff + px * XSTR + (nT[4] << 6) + (oct << 3)) = r;
        }
        #pragma unroll
        for (int ks = 12; ks < 18; ++ks)
            bfrag[ks] = *(const short8*)(brow + ks * 32);
    }
    __syncthreads();

    // ================= Stage 4: conv MFMA (LDS-only waits) + epilogue =========
    float4a acc = {0.f, 0.f, 0.f, 0.f};
    {
        const unsigned short* arow = s_xoff + l16 * XSTR + quad * 8;
        #pragma unroll
        for (int ks = 0; ks < 18; ++ks) {
            const short8 a = *(const short8*)(arow + ks * 32);
            acc = __builtin_amdgcn_mfma_f32_16x16x32_bf16(a, bfrag[ks], acc, 0, 0, 0);
        }
    }
    // D layout: col = oc = wave*16 + l16; row = px = quad*4 + r  (r = acc idx)
    const int o = wave * 16 + l16;
    if (nhwc_out) {
        // col=o contiguous in NHWC -> bf16 scalar stores (as round-0)
        unsigned short* ob = (unsigned short*)out + ((size_t)b << 22);
        unsigned short* orow = ob + ((((h << 8) + w0) << 6)) + o;
        #pragma unroll
        for (int r = 0; r < 4; ++r) {
            float v = acc[r];
            if (relu) v = fmaxf(v, 0.f);
            orow[(size_t)((quad * 4 + r) << 6)] = f2bf(v);
        }
    } else {
        // NCHW fp32 direct: acc IS a contiguous px-quad float4 for channel o.
        // No LDS transpose, no extra barrier.
        float* obf = (float*)out + ((size_t)b << 22);
        const int gidx = (o << 16) + (h << 8) + w0 + (quad << 2);
        float v0 = acc[0], v1 = acc[1], v2 = acc[2], v3 = acc[3];
        if (relu) {
            v0 = fmaxf(v0, 0.f); v1 = fmaxf(v1, 0.f);
            v2 = fmaxf(v2, 0.f); v3 = fmaxf(v3, 0.f);
        }
        if (addsrc != nullptr) {
            const float4 rv = *(const float4*)(addsrc + ((size_t)b << 22) + gidx);
            v0 += rv.x; v1 += rv.y; v2 += rv.z; v3 += rv.w;
        }
        float4 vv; vv.x = v0; vv.y = v1; vv.z = v2; vv.w = v3;
        *(float4*)(obf + gidx) = vv;
    }
}

// ---------------------------------------------------------------------------
extern "C" void kernel_launch(void* const* d_in, const int* in_sizes, int n_in,
                              void* d_out, int out_size, void* d_ws, size_t ws_size,
                              hipStream_t stream) {
    const float* x      = (const float*)d_in[0];
    const float* w_off1 = (const float*)d_in[1];
    const float* b_off1 = (const float*)d_in[2];
    const float* w1     = (const float*)d_in[3];
    const float* w_off2 = (const float*)d_in[4];
    const float* b_off2 = (const float*)d_in[5];
    const float* w2     = (const float*)d_in[6];
    float* outp = (float*)d_out;

    // workspace: 16 MB xT(bf16) + 16 MB midT(bf16) + packed weights = 32.2 MB
    char* ws = (char*)d_ws;
    unsigned short* xT   = (unsigned short*)ws;                     // 16777216 B
    unsigned short* midT = (unsigned short*)(ws + 16777216);        // 16777216 B
    unsigned short* w1b  = (unsigned short*)(ws + 33554432);                    // 73728
    unsigned short* w2b  = (unsigned short*)(ws + 33554432 + 73728);            // 73728
    unsigned short* wob1 = (unsigned short*)(ws + 33554432 + 2 * 73728);        // 36864
    unsigned short* wob2 = (unsigned short*)(ws + 33554432 + 2 * 73728 + 36864);// 36864

    k_pack_all<<<432, 256, 0, stream>>>(w1, w2, w_off1, w_off2, w1b, w2b, wob1, wob2);

    dim3 gT(1024, 2);
    k_transpose_bf<<<gT, 256, 0, stream>>>(x, xT);

    dim3 gDef(16, 256, 2);   // (W/16, H, B)
    // layer 1: offsets + deform-conv(x), ReLU -> midT (NHWC bf16)
    k_fused<<<gDef, 256, 0, stream>>>(xT, wob1, b_off1, w1b, nullptr, midT, 1, 1);
    // layer 2: offsets + deform-conv(mid), + x residual -> out (NCHW fp32)
    k_fused<<<gDef, 256, 0, stream>>>(midT, wob2, b_off2, w2b, x, outp, 0, 0);
}